// Round 3
// baseline (478.558 us; speedup 1.0000x reference)
//
#include <hip/hip_runtime.h>
#include <math.h>

typedef unsigned short u16;
typedef unsigned int u32;
typedef __attribute__((ext_vector_type(8))) short short8;   // 8 bf16 = 4 VGPRs
typedef __attribute__((ext_vector_type(4))) float float4v;  // MFMA accum

// ---------- constants ----------
#define BATCH   8192
#define OBS     21
#define HID     512
#define NL      10
#define OVERALL 5632            // HID*(NL+1)
#define IN_DIM  5653            // OBS + OVERALL
#define ACT     8

// output element offsets (flat concat, fp32 elements)
#define O_PM   0
#define O_LS   65536
#define O_NH   131072
#define O_NM   (131072 + BATCH*OVERALL)     // 46268416
#define O_NLS  (O_NM + 65536)               // 46333952

// packed workspace: 10 x 512 x 512 bf16 weight blocks (K-contiguous)
#define WSP_TOTAL (10*512*512)
#define WSP_BYTES ((size_t)WSP_TOTAL * 2)

__device__ __forceinline__ u16 f2bf(float f) {
    u32 u = __float_as_uint(f);
    u32 r = (u + 0x7fffu + ((u >> 16) & 1u)) >> 16;   // RNE
    return (u16)r;
}
__device__ __forceinline__ u32 pkbf(float a, float b) {
    return (u32)f2bf(a) | ((u32)f2bf(b) << 16);
}
__device__ __forceinline__ void gload_lds16(const void* g, void* l) {
    __builtin_amdgcn_global_load_lds(
        (const __attribute__((address_space(1))) char*)g,
        (__attribute__((address_space(3))) char*)l, 16, 0, 0);
}
__device__ __forceinline__ int swz4(int r) { return (r + (r >> 2)) & 3; }

// ---------- kernel 0: repack banded W_mean blocks fp32 -> bf16 ----------
__global__ __launch_bounds__(256) void k_pack(const float* __restrict__ Wm,
                                              u16* __restrict__ ws) {
    int idx = blockIdx.x * 256 + threadIdx.x;
    if (idx >= WSP_TOTAL) return;
    int z = idx >> 18;
    int rem = idx & 262143;
    int n = rem >> 9, k = rem & 511;
    float v = Wm[(size_t)(512 * (z + 1) + n) * IN_DIM + OBS + 512 * z + k];
    ws[idx] = f2bf(v);
}

// ---------- kernel 1: fused slice kernel -----------------------------------
// grid (128, 11): block = 64 batch rows (gm) x one 512-col X slice (z).
// 8 waves / 512 threads: regs 64 VGPR + 64 AGPR = 128/thread -> 4 waves/SIMD
// -> TWO co-resident blocks per CU. While one block drains vmcnt(0) at its
// barrier, the other computes (m114 wave-level overlap) — the occupancy fix
// the 16-wave version could not have (it filled the CU alone).
//  z<10 : GEMM band z+1 (BN=512, waves 0-7) + logstd partial (waves 0-3)
//  z==10: logstd partial (waves 0-3) + new_mean band 11 (waves 4-7)
#define BM 64
#define BK 32
#define LDA 40                  // padded bf16 LDS rows for A
__global__ __launch_bounds__(512, 4) void k_fused(
        const float* __restrict__ X,
        const float* __restrict__ Wm_raw,
        const u16* __restrict__ Wp,
        const float* __restrict__ Wls_raw,
        const float* __restrict__ b_mean,
        float* __restrict__ out_h,
        float* __restrict__ out_ls,
        float* __restrict__ out_mean,
        int packed) {
    __shared__ __attribute__((aligned(16))) u16 As[BM * LDA];      // 5.1 KB
    __shared__ __attribute__((aligned(16))) u16 Bs[512 * 32];      // 32 KB
    __shared__ __attribute__((aligned(16))) u16 Wt[16 * 520];      // 16.25 KB
    u16* Wt2 = (u16*)Bs;                     // z==10 only: mean slice aliases Bs

    int t = threadIdx.x;
    int w = t >> 6, lane = t & 63;
    int quad = lane >> 4, r16 = lane & 15;
    int gm = blockIdx.x * BM;
    int z = blockIdx.y;
    bool mainz = (z < 10);
    int wn = w * 64;                         // wave n-tile (wave m-tile = 0)

    // ---- stage logstd slice (bf16) + (z==10) mean slice ----
    {
        int n = t >> 6;                      // 0..7
        int k8 = (t & 63) * 8;
        const float* wr = Wls_raw + (size_t)n * IN_DIM + OBS + z * 512 + k8;
        u16* dst = &Wt[n * 520 + k8];
#pragma unroll
        for (int q = 0; q < 8; ++q) dst[q] = f2bf(wr[q]);
        if (!mainz) {
            const float* wr2 = Wm_raw + (size_t)(OVERALL + n) * IN_DIM + OBS + z * 512 + k8;
            u16* d2 = &Wt2[n * 520 + k8];
#pragma unroll
            for (int q = 0; q < 8; ++q) d2[q] = f2bf(wr2[q]);
        }
    }

    // ---- A prefetch pointer: 1 float4 per thread per chunk ----
    int arow = t >> 3;                       // 0..63
    int acol = (t & 7) * 4;                  // 0..28
    const float* gA = X + (size_t)(gm + arow) * OVERALL + (size_t)z * 512 + acol;
    float4 areg = *(const float4*)(gA);      // chunk 0

    float4v acc[4][4];
#pragma unroll
    for (int i = 0; i < 4; i++)
#pragma unroll
        for (int j = 0; j < 4; j++) acc[i][j] = (float4v)0.f;
    float4v accE = (float4v)0.f;             // logstd (w<4) or mean (z==10, w>=4)

    for (int it = 0; it < 16; ++it) {
        int k0 = it * BK;
        __syncthreads();                     // prev frag reads done; LDS reusable
        // ---- A: cvt prefetched regs -> bf16 LDS ----
        {
            uint2 p;
            p.x = pkbf(areg.x, areg.y);
            p.y = pkbf(areg.z, areg.w);
            *(uint2*)&As[arow * LDA + acol] = p;
        }
        // ---- B: global -> LDS, xor-swizzled slots ----
        if (mainz) {
            if (packed) {
#pragma unroll
                for (int i2 = 0; i2 < 4; ++i2) {
                    int base_row = i2 * 128 + w * 16;
                    int row = base_row + (lane >> 2);
                    int slot = lane & 3;
                    int j = (slot - swz4(row)) & 3;    // logical k-chunk in slot
                    const u16* g = Wp + (size_t)z * 262144 + (size_t)row * 512 + k0 + j * 8;
                    gload_lds16(g, (char*)Bs + base_row * 64);
                }
            } else {
#pragma unroll
                for (int i2 = 0; i2 < 4; ++i2) {
                    int row = i2 * 128 + w * 16 + (lane >> 2);
                    int slot = lane & 3;
                    int j = (slot - swz4(row)) & 3;
                    const float* g = Wm_raw + (size_t)(512 * (z + 1) + row) * IN_DIM
                                     + OBS + (size_t)z * 512 + k0 + j * 8;
                    uint4 q;
                    q.x = pkbf(g[0], g[1]); q.y = pkbf(g[2], g[3]);
                    q.z = pkbf(g[4], g[5]); q.w = pkbf(g[6], g[7]);
                    *(uint4*)&Bs[row * 32 + slot * 8] = q;
                }
            }
        }
        __syncthreads();                     // tile visible (drains B loads)
        if (it < 15) areg = *(const float4*)(gA + (it + 1) * BK);  // covered by MFMA

        if (mainz) {
            short8 bfr[4];
#pragma unroll
            for (int j = 0; j < 4; j++) {
                int n = wn + j * 16 + r16;
                int s = (quad + swz4(n)) & 3;
                bfr[j] = *(const short8*)&Bs[n * 32 + s * 8];
            }
#pragma unroll
            for (int i2 = 0; i2 < 4; i2++) {
                short8 af = *(const short8*)&As[(i2 * 16 + r16) * LDA + quad * 8];
#pragma unroll
                for (int j = 0; j < 4; j++)
                    acc[i2][j] = __builtin_amdgcn_mfma_f32_16x16x32_bf16(af, bfr[j], acc[i2][j], 0, 0, 0);
            }
        }
        if (w < 4) {                         // logstd partial: rows w*16..w*16+15
            short8 aL = *(const short8*)&As[(w * 16 + r16) * LDA + quad * 8];
            short8 bL = *(const short8*)&Wt[r16 * 520 + k0 + quad * 8];
            accE = __builtin_amdgcn_mfma_f32_16x16x32_bf16(aL, bL, accE, 0, 0, 0);
        } else if (!mainz) {                 // mean band: rows (w-4)*16..
            short8 aL = *(const short8*)&As[((w - 4) * 16 + r16) * LDA + quad * 8];
            short8 bL = *(const short8*)&Wt2[r16 * 520 + k0 + quad * 8];
            accE = __builtin_amdgcn_mfma_f32_16x16x32_bf16(aL, bL, accE, 0, 0, 0);
        }
    }

    // ---- epilogues.  C/D layout: col = lane&15, row = quad*4 + reg ----
    if (mainz) {
        int colblock = (z + 1) * 512;
#pragma unroll
        for (int j = 0; j < 4; j++) {
            int n_loc = wn + j * 16 + r16;
            float bias = b_mean[colblock + n_loc];
#pragma unroll
            for (int i2 = 0; i2 < 4; i2++) {
                int m0 = gm + i2 * 16 + quad * 4;
#pragma unroll
                for (int r = 0; r < 4; r++) {
                    float v = acc[i2][j][r] + bias;
                    out_h[(size_t)(m0 + r) * OVERALL + colblock + n_loc] = fmaxf(v, 0.f);
                }
            }
        }
    }
    if (w < 4) {                             // logstd partial -> atomic
        if (r16 < ACT) {
#pragma unroll
            for (int r = 0; r < 4; r++) {
                int row = gm + w * 16 + quad * 4 + r;
                atomicAdd(&out_ls[(size_t)row * ACT + r16], accE[r]);
            }
        }
    } else if (!mainz) {                     // mean: exact, direct store
        if (r16 < ACT) {
            float bias = b_mean[OVERALL + r16];
#pragma unroll
            for (int r = 0; r < 4; r++) {
                int row = gm + (w - 4) * 16 + quad * 4 + r;
                out_mean[(size_t)row * ACT + r16] = accE[r] + bias;
            }
        }
    }
}

// ---------- kernel 2: band block 0 (obs -> new_hidden cols 0..511) ----------
#define B0_ROWS 32
__global__ __launch_bounds__(256) void k_block0(const float* __restrict__ obs,
                                                const float* __restrict__ Wm,
                                                const float* __restrict__ b_mean,
                                                float* __restrict__ out_h) {
    __shared__ float w0[OBS * 512];           // transposed [k][n]
    __shared__ float bias_s[512];
    __shared__ float obs_s[B0_ROWS * OBS];
    int t = threadIdx.x;
    int b0 = blockIdx.x * B0_ROWS;
    for (int i = t; i < OBS * 512; i += 256) {
        int n = i / OBS, k = i - n * OBS;
        w0[k * 512 + n] = Wm[(size_t)n * IN_DIM + k];
    }
    for (int i = t; i < 512; i += 256) bias_s[i] = b_mean[i];
    for (int i = t; i < B0_ROWS * OBS; i += 256) obs_s[i] = obs[(size_t)b0 * OBS + i];
    __syncthreads();

    int n0 = (t & 127) * 4;
    int rh = t >> 7;
#pragma unroll 4
    for (int r = 0; r < 16; r++) {
        int row = rh * 16 + r;
        float acc0 = bias_s[n0], acc1 = bias_s[n0 + 1];
        float acc2 = bias_s[n0 + 2], acc3 = bias_s[n0 + 3];
#pragma unroll
        for (int k = 0; k < OBS; k++) {
            float xo = obs_s[row * OBS + k];
            const float* wr = &w0[k * 512 + n0];
            acc0 += xo * wr[0]; acc1 += xo * wr[1];
            acc2 += xo * wr[2]; acc3 += xo * wr[3];
        }
        float4 o;
        o.x = fmaxf(acc0, 0.f); o.y = fmaxf(acc1, 0.f);
        o.z = fmaxf(acc2, 0.f); o.w = fmaxf(acc3, 0.f);
        *(float4*)&out_h[(size_t)(b0 + row) * OVERALL + n0] = o;
    }
}

// ---------- kernel 3: finisher: logstd obs-part + bias, tanh, copy ----------
__global__ __launch_bounds__(256) void k_finish(const float* __restrict__ obs,
                                                const float* __restrict__ Wls,
                                                const float* __restrict__ b_logstd,
                                                const float* __restrict__ pm,
                                                const float* __restrict__ pls,
                                                float* __restrict__ o_pm,
                                                float* __restrict__ o_lstd,
                                                float* __restrict__ o_nls) {
    __shared__ float wobs[ACT * OBS];
    __shared__ float bls[ACT];
    int t = threadIdx.x;
    if (t < ACT * OBS) wobs[t] = Wls[(size_t)(t / OBS) * IN_DIM + (t % OBS)];
    if (t < ACT) bls[t] = b_logstd[t];
    __syncthreads();
    int row = blockIdx.x * 256 + t;           // 8192 rows
    float ob[OBS];
#pragma unroll
    for (int k = 0; k < OBS; k++) ob[k] = obs[(size_t)row * OBS + k];
#pragma unroll
    for (int n = 0; n < ACT; n++) {
        float a = bls[n];
#pragma unroll
        for (int k = 0; k < OBS; k++) a += ob[k] * wobs[n * OBS + k];
        o_nls[(size_t)row * ACT + n] += a;    // completes the atomic partials
    }
    // prev_mean copy + log_std tanh transform
    float4 p0 = *(const float4*)(pm + (size_t)row * ACT);
    float4 p1 = *(const float4*)(pm + (size_t)row * ACT + 4);
    *(float4*)(o_pm + (size_t)row * ACT) = p0;
    *(float4*)(o_pm + (size_t)row * ACT + 4) = p1;
    float4 l0 = *(const float4*)(pls + (size_t)row * ACT);
    float4 l1 = *(const float4*)(pls + (size_t)row * ACT + 4);
    float4 q0, q1;
    q0.x = -5.f + 3.5f * (tanhf(l0.x) + 1.f);
    q0.y = -5.f + 3.5f * (tanhf(l0.y) + 1.f);
    q0.z = -5.f + 3.5f * (tanhf(l0.z) + 1.f);
    q0.w = -5.f + 3.5f * (tanhf(l0.w) + 1.f);
    q1.x = -5.f + 3.5f * (tanhf(l1.x) + 1.f);
    q1.y = -5.f + 3.5f * (tanhf(l1.y) + 1.f);
    q1.z = -5.f + 3.5f * (tanhf(l1.z) + 1.f);
    q1.w = -5.f + 3.5f * (tanhf(l1.w) + 1.f);
    *(float4*)(o_lstd + (size_t)row * ACT) = q0;
    *(float4*)(o_lstd + (size_t)row * ACT + 4) = q1;
}

extern "C" void kernel_launch(void* const* d_in, const int* in_sizes, int n_in,
                              void* d_out, int out_size, void* d_ws, size_t ws_size,
                              hipStream_t stream) {
    const float* obs         = (const float*)d_in[0];
    const float* hidden0     = (const float*)d_in[1];
    const float* prev_mean   = (const float*)d_in[2];
    const float* prev_logstd = (const float*)d_in[3];
    const float* W_mean      = (const float*)d_in[4];
    const float* b_mean      = (const float*)d_in[5];
    const float* W_logstd    = (const float*)d_in[6];
    const float* b_logstd    = (const float*)d_in[7];

    float* out   = (float*)d_out;
    float* o_pm  = out + O_PM;
    float* o_ls  = out + O_LS;
    float* o_nh  = out + O_NH;
    float* o_nm  = out + O_NM;
    float* o_nls = out + O_NLS;
    u16*   ws    = (u16*)d_ws;

    int packed = (ws != nullptr && ws_size >= WSP_BYTES) ? 1 : 0;

    if (packed) {
        k_pack<<<(WSP_TOTAL + 255) / 256, 256, 0, stream>>>(W_mean, ws);
    }
    hipMemsetAsync(o_nls, 0, (size_t)BATCH * ACT * sizeof(float), stream);
    k_fused<<<dim3(BATCH / BM, NL + 1), 512, 0, stream>>>(
        hidden0, W_mean, ws, W_logstd, b_mean, o_nh, o_nls, o_nm, packed);
    k_block0<<<BATCH / B0_ROWS, 256, 0, stream>>>(obs, W_mean, b_mean, o_nh);
    k_finish<<<BATCH / 256, 256, 0, stream>>>(obs, W_logstd, b_logstd,
                                              prev_mean, prev_logstd,
                                              o_pm, o_ls, o_nls);
}

// Round 4
// 474.162 us; speedup vs baseline: 1.0093x; 1.0093x over previous
//
#include <hip/hip_runtime.h>
#include <math.h>

typedef unsigned short u16;
typedef unsigned int u32;
typedef __attribute__((ext_vector_type(8))) short short8;   // 8 bf16 = 4 VGPRs
typedef __attribute__((ext_vector_type(4))) float float4v;  // MFMA accum

// ---------- constants ----------
#define BATCH   8192
#define OBS     21
#define HID     512
#define NL      10
#define OVERALL 5632            // HID*(NL+1)
#define IN_DIM  5653            // OBS + OVERALL
#define ACT     8

// output element offsets (flat concat, fp32 elements)
#define O_PM   0
#define O_LS   65536
#define O_NH   131072
#define O_NM   (131072 + BATCH*OVERALL)     // 46268416
#define O_NLS  (O_NM + 65536)               // 46333952

// packed workspace: 10 x 512 x 512 bf16 weight blocks (K-contiguous)
#define WSP_TOTAL (10*512*512)
#define WSP_BYTES ((size_t)WSP_TOTAL * 2)

__device__ __forceinline__ u16 f2bf(float f) {
    u32 u = __float_as_uint(f);
    u32 r = (u + 0x7fffu + ((u >> 16) & 1u)) >> 16;   // RNE
    return (u16)r;
}
__device__ __forceinline__ u32 pkbf(float a, float b) {
    return (u32)f2bf(a) | ((u32)f2bf(b) << 16);
}
__device__ __forceinline__ void gload_lds16(const void* g, void* l) {
    __builtin_amdgcn_global_load_lds(
        (const __attribute__((address_space(1))) char*)g,
        (__attribute__((address_space(3))) char*)l, 16, 0, 0);
}
// convert 16 consecutive fp32 -> 16 bf16 (two uint4 stores)
__device__ __forceinline__ void cvt16(const float* __restrict__ g, u16* dst) {
    float4 f0 = *(const float4*)(g);
    float4 f1 = *(const float4*)(g + 4);
    float4 f2 = *(const float4*)(g + 8);
    float4 f3 = *(const float4*)(g + 12);
    uint4 q0, q1;
    q0.x = pkbf(f0.x, f0.y); q0.y = pkbf(f0.z, f0.w);
    q0.z = pkbf(f1.x, f1.y); q0.w = pkbf(f1.z, f1.w);
    q1.x = pkbf(f2.x, f2.y); q1.y = pkbf(f2.z, f2.w);
    q1.z = pkbf(f3.x, f3.y); q1.w = pkbf(f3.z, f3.w);
    *(uint4*)dst = q0;
    *(uint4*)(dst + 8) = q1;
}

// ---------- kernel 0: repack banded W_mean blocks fp32 -> bf16 ----------
__global__ __launch_bounds__(256) void k_pack(const float* __restrict__ Wm,
                                              u16* __restrict__ ws) {
    int idx = blockIdx.x * 256 + threadIdx.x;
    if (idx >= WSP_TOTAL) return;
    int z = idx >> 18;
    int rem = idx & 262143;
    int n = rem >> 9, k = rem & 511;
    float v = Wm[(size_t)(512 * (z + 1) + n) * IN_DIM + OBS + 512 * z + k];
    ws[idx] = f2bf(v);
}

// ---------- kernel 1: fused slice kernel -----------------------------------
// m97-shape: 256-thread / 4-wave blocks, block tile 128x128, 3 blocks/CU =
// 3 INDEPENDENT barrier groups per CU (m114 overlap — the latency-hiding that
// one monolithic 16-wave group cannot provide).
// grid (64, 41):
//  y<40 : z = y>>2, h = y&3 -> GEMM band z+1, n-cols [h*128, h*128+128).
//         h==0 blocks additionally accumulate the logstd partial for slice z.
//         h-siblings share the same X slice; same linear-id mod 8 -> same XCD
//         -> X served once from L2 (check: FETCH_SIZE).
//  y==40: z=10 slice: logstd partial + new_mean band 11.
#define BM 128
#define BK 32
#define LDA 40                  // 80 B rows: 16B-aligned, balanced banks
__global__ __launch_bounds__(256, 3) void k_fused(
        const float* __restrict__ X,
        const float* __restrict__ Wm_raw,
        const u16* __restrict__ Wp,
        const float* __restrict__ Wls_raw,
        const float* __restrict__ b_mean,
        float* __restrict__ out_h,
        float* __restrict__ out_ls,
        float* __restrict__ out_mean,
        int packed) {
    __shared__ __attribute__((aligned(16))) u16 As[BM * LDA];     // 10 KB
    __shared__ __attribute__((aligned(16))) u16 Bs[128 * 32];     // 8 KB
    __shared__ __attribute__((aligned(16))) u16 Wt[8 * 520];      // 8.125 KB
    __shared__ __attribute__((aligned(16))) u16 Wt2[8 * 520];     // 8.125 KB

    const int t = threadIdx.x;
    const int w = t >> 6, lane = t & 63;
    const int quad = lane >> 4, r16 = lane & 15;
    const int gm = blockIdx.x * BM;
    const int y = blockIdx.y;
    const bool mainz = (y < 40);
    const int z = mainz ? (y >> 2) : 10;
    const int h = y & 3;                     // n-quarter (mainz only)
    const bool do_ls = (!mainz) || (h == 0);
    const int wm = (w >> 1) * 64;            // wave tile: 2m x 2n of 64x64
    const int wn = (w & 1) * 64;

    // ---- stage logstd slice (8 rows x 512 k, bf16) + (y40) mean slice ----
    if (do_ls) {
        int n = t >> 5;                      // 0..7
        int k16 = (t & 31) * 16;
        cvt16(Wls_raw + (size_t)n * IN_DIM + OBS + z * 512 + k16, &Wt[n * 520 + k16]);
    }
    if (!mainz) {
        int n = t >> 5;
        int k16 = (t & 31) * 16;
        cvt16(Wm_raw + (size_t)(OVERALL + n) * IN_DIM + OBS + z * 512 + k16,
              &Wt2[n * 520 + k16]);
    }

    // ---- A: each thread owns half a row-slice (16 floats / step) ----
    const int arow = t >> 1;                 // 0..127
    const int ahalf = (t & 1) * 16;          // fp32 col offset within K-step
    const float* gA = X + (size_t)(gm + arow) * OVERALL + (size_t)z * 512 + ahalf;
    float4 a0 = *(const float4*)(gA);
    float4 a1 = *(const float4*)(gA + 4);
    float4 a2 = *(const float4*)(gA + 8);
    float4 a3 = *(const float4*)(gA + 12);

    float4v acc[4][4];
#pragma unroll
    for (int i = 0; i < 4; i++)
#pragma unroll
        for (int j = 0; j < 4; j++) acc[i][j] = (float4v)0.f;
    float4v accL[2], accM[2];
    accL[0] = (float4v)0.f; accL[1] = (float4v)0.f;
    accM[0] = (float4v)0.f; accM[1] = (float4v)0.f;

    for (int it = 0; it < 16; ++it) {
        const int k0 = it * BK;
        __syncthreads();                     // prev frag reads done; LDS reusable
        // ---- A: cvt prefetched regs -> bf16 LDS (16 bf16 per thread) ----
        {
            uint4 qa, qb;
            qa.x = pkbf(a0.x, a0.y); qa.y = pkbf(a0.z, a0.w);
            qa.z = pkbf(a1.x, a1.y); qa.w = pkbf(a1.z, a1.w);
            qb.x = pkbf(a2.x, a2.y); qb.y = pkbf(a2.z, a2.w);
            qb.z = pkbf(a3.x, a3.y); qb.w = pkbf(a3.z, a3.w);
            u16* dst = &As[arow * LDA + ahalf];
            *(uint4*)dst = qa;
            *(uint4*)(dst + 8) = qb;
        }
        // ---- B: global -> LDS (linear dest: lane*16 == row-major layout) ----
        if (mainz) {
            if (packed) {
#pragma unroll
                for (int i2 = 0; i2 < 2; ++i2) {
                    int seg = w * 2 + i2;            // 8 segments of 16 rows
                    const u16* g = Wp + (size_t)z * 262144
                                   + (size_t)(h * 128 + seg * 16 + (lane >> 2)) * 512
                                   + k0 + (lane & 3) * 8;
                    gload_lds16(g, (char*)Bs + seg * 1024);
                }
            } else {
                int rowi = t >> 1;
                int half16 = (t & 1) * 16;
                const float* g = Wm_raw
                    + (size_t)(512 * (z + 1) + h * 128 + rowi) * IN_DIM
                    + OBS + (size_t)z * 512 + k0 + half16;
                cvt16(g, &Bs[rowi * 32 + half16]);
            }
        }
        __syncthreads();                     // tile visible (drains B loads)
        if (it < 15) {                       // prefetch next A (covered by MFMA)
            a0 = *(const float4*)(gA + (it + 1) * BK);
            a1 = *(const float4*)(gA + (it + 1) * BK + 4);
            a2 = *(const float4*)(gA + (it + 1) * BK + 8);
            a3 = *(const float4*)(gA + (it + 1) * BK + 12);
        }

        if (mainz) {
            short8 bfr[4];
#pragma unroll
            for (int j = 0; j < 4; j++) {
                int n = wn + j * 16 + r16;
                bfr[j] = *(const short8*)&Bs[n * 32 + quad * 8];
            }
#pragma unroll
            for (int i2 = 0; i2 < 4; i2++) {
                short8 af = *(const short8*)&As[(wm + i2 * 16 + r16) * LDA + quad * 8];
#pragma unroll
                for (int j = 0; j < 4; j++)
                    acc[i2][j] = __builtin_amdgcn_mfma_f32_16x16x32_bf16(af, bfr[j], acc[i2][j], 0, 0, 0);
            }
        }
        if (do_ls) {                         // logstd partial: wave w rows w*32..+31
            short8 bL = *(const short8*)&Wt[(r16 & 7) * 520 + k0 + quad * 8];
            short8 aL0 = *(const short8*)&As[(w * 32 + r16) * LDA + quad * 8];
            short8 aL1 = *(const short8*)&As[(w * 32 + 16 + r16) * LDA + quad * 8];
            accL[0] = __builtin_amdgcn_mfma_f32_16x16x32_bf16(aL0, bL, accL[0], 0, 0, 0);
            accL[1] = __builtin_amdgcn_mfma_f32_16x16x32_bf16(aL1, bL, accL[1], 0, 0, 0);
            if (!mainz) {                    // mean band shares the A frags
                short8 bM = *(const short8*)&Wt2[(r16 & 7) * 520 + k0 + quad * 8];
                accM[0] = __builtin_amdgcn_mfma_f32_16x16x32_bf16(aL0, bM, accM[0], 0, 0, 0);
                accM[1] = __builtin_amdgcn_mfma_f32_16x16x32_bf16(aL1, bM, accM[1], 0, 0, 0);
            }
        }
    }

    // ---- epilogues.  C/D layout: col = lane&15, row = quad*4 + reg ----
    if (mainz) {
        int colblock = (z + 1) * 512 + h * 128;
#pragma unroll
        for (int j = 0; j < 4; j++) {
            int n_loc = wn + j * 16 + r16;
            float bias = b_mean[colblock + n_loc];
#pragma unroll
            for (int i2 = 0; i2 < 4; i2++) {
                int m0 = gm + wm + i2 * 16 + quad * 4;
#pragma unroll
                for (int r = 0; r < 4; r++) {
                    float v = acc[i2][j][r] + bias;
                    out_h[(size_t)(m0 + r) * OVERALL + colblock + n_loc] = fmaxf(v, 0.f);
                }
            }
        }
    }
    if (do_ls && r16 < ACT) {                // logstd partial -> atomic
#pragma unroll
        for (int s = 0; s < 2; ++s)
#pragma unroll
            for (int r = 0; r < 4; r++) {
                int row = gm + w * 32 + s * 16 + quad * 4 + r;
                atomicAdd(&out_ls[(size_t)row * ACT + r16], accL[s][r]);
            }
    }
    if (!mainz && r16 < ACT) {               // mean: exact, direct store
        float bias = b_mean[OVERALL + r16];
#pragma unroll
        for (int s = 0; s < 2; ++s)
#pragma unroll
            for (int r = 0; r < 4; r++) {
                int row = gm + w * 32 + s * 16 + quad * 4 + r;
                out_mean[(size_t)row * ACT + r16] = accM[s][r] + bias;
            }
    }
}

// ---------- kernel 2: band block 0 (obs -> new_hidden cols 0..511) ----------
#define B0_ROWS 32
__global__ __launch_bounds__(256) void k_block0(const float* __restrict__ obs,
                                                const float* __restrict__ Wm,
                                                const float* __restrict__ b_mean,
                                                float* __restrict__ out_h) {
    __shared__ float w0[OBS * 512];           // transposed [k][n]
    __shared__ float bias_s[512];
    __shared__ float obs_s[B0_ROWS * OBS];
    int t = threadIdx.x;
    int b0 = blockIdx.x * B0_ROWS;
    for (int i = t; i < OBS * 512; i += 256) {
        int n = i / OBS, k = i - n * OBS;
        w0[k * 512 + n] = Wm[(size_t)n * IN_DIM + k];
    }
    for (int i = t; i < 512; i += 256) bias_s[i] = b_mean[i];
    for (int i = t; i < B0_ROWS * OBS; i += 256) obs_s[i] = obs[(size_t)b0 * OBS + i];
    __syncthreads();

    int n0 = (t & 127) * 4;
    int rh = t >> 7;
#pragma unroll 4
    for (int r = 0; r < 16; r++) {
        int row = rh * 16 + r;
        float acc0 = bias_s[n0], acc1 = bias_s[n0 + 1];
        float acc2 = bias_s[n0 + 2], acc3 = bias_s[n0 + 3];
#pragma unroll
        for (int k = 0; k < OBS; k++) {
            float xo = obs_s[row * OBS + k];
            const float* wr = &w0[k * 512 + n0];
            acc0 += xo * wr[0]; acc1 += xo * wr[1];
            acc2 += xo * wr[2]; acc3 += xo * wr[3];
        }
        float4 o;
        o.x = fmaxf(acc0, 0.f); o.y = fmaxf(acc1, 0.f);
        o.z = fmaxf(acc2, 0.f); o.w = fmaxf(acc3, 0.f);
        *(float4*)&out_h[(size_t)(b0 + row) * OVERALL + n0] = o;
    }
}

// ---------- kernel 3: finisher: logstd obs-part + bias, tanh, copy ----------
__global__ __launch_bounds__(256) void k_finish(const float* __restrict__ obs,
                                                const float* __restrict__ Wls,
                                                const float* __restrict__ b_logstd,
                                                const float* __restrict__ pm,
                                                const float* __restrict__ pls,
                                                float* __restrict__ o_pm,
                                                float* __restrict__ o_lstd,
                                                float* __restrict__ o_nls) {
    __shared__ float wobs[ACT * OBS];
    __shared__ float bls[ACT];
    int t = threadIdx.x;
    if (t < ACT * OBS) wobs[t] = Wls[(size_t)(t / OBS) * IN_DIM + (t % OBS)];
    if (t < ACT) bls[t] = b_logstd[t];
    __syncthreads();
    int row = blockIdx.x * 256 + t;           // 8192 rows
    float ob[OBS];
#pragma unroll
    for (int k = 0; k < OBS; k++) ob[k] = obs[(size_t)row * OBS + k];
#pragma unroll
    for (int n = 0; n < ACT; n++) {
        float a = bls[n];
#pragma unroll
        for (int k = 0; k < OBS; k++) a += ob[k] * wobs[n * OBS + k];
        o_nls[(size_t)row * ACT + n] += a;    // completes the atomic partials
    }
    // prev_mean copy + log_std tanh transform
    float4 p0 = *(const float4*)(pm + (size_t)row * ACT);
    float4 p1 = *(const float4*)(pm + (size_t)row * ACT + 4);
    *(float4*)(o_pm + (size_t)row * ACT) = p0;
    *(float4*)(o_pm + (size_t)row * ACT + 4) = p1;
    float4 l0 = *(const float4*)(pls + (size_t)row * ACT);
    float4 l1 = *(const float4*)(pls + (size_t)row * ACT + 4);
    float4 q0, q1;
    q0.x = -5.f + 3.5f * (tanhf(l0.x) + 1.f);
    q0.y = -5.f + 3.5f * (tanhf(l0.y) + 1.f);
    q0.z = -5.f + 3.5f * (tanhf(l0.z) + 1.f);
    q0.w = -5.f + 3.5f * (tanhf(l0.w) + 1.f);
    q1.x = -5.f + 3.5f * (tanhf(l1.x) + 1.f);
    q1.y = -5.f + 3.5f * (tanhf(l1.y) + 1.f);
    q1.z = -5.f + 3.5f * (tanhf(l1.z) + 1.f);
    q1.w = -5.f + 3.5f * (tanhf(l1.w) + 1.f);
    *(float4*)(o_lstd + (size_t)row * ACT) = q0;
    *(float4*)(o_lstd + (size_t)row * ACT + 4) = q1;
}

extern "C" void kernel_launch(void* const* d_in, const int* in_sizes, int n_in,
                              void* d_out, int out_size, void* d_ws, size_t ws_size,
                              hipStream_t stream) {
    const float* obs         = (const float*)d_in[0];
    const float* hidden0     = (const float*)d_in[1];
    const float* prev_mean   = (const float*)d_in[2];
    const float* prev_logstd = (const float*)d_in[3];
    const float* W_mean      = (const float*)d_in[4];
    const float* b_mean      = (const float*)d_in[5];
    const float* W_logstd    = (const float*)d_in[6];
    const float* b_logstd    = (const float*)d_in[7];

    float* out   = (float*)d_out;
    float* o_pm  = out + O_PM;
    float* o_ls  = out + O_LS;
    float* o_nh  = out + O_NH;
    float* o_nm  = out + O_NM;
    float* o_nls = out + O_NLS;
    u16*   ws    = (u16*)d_ws;

    int packed = (ws != nullptr && ws_size >= WSP_BYTES) ? 1 : 0;

    if (packed) {
        k_pack<<<(WSP_TOTAL + 255) / 256, 256, 0, stream>>>(W_mean, ws);
    }
    hipMemsetAsync(o_nls, 0, (size_t)BATCH * ACT * sizeof(float), stream);
    k_fused<<<dim3(BATCH / BM, 41), 256, 0, stream>>>(
        hidden0, W_mean, ws, W_logstd, b_mean, o_nh, o_nls, o_nm, packed);
    k_block0<<<BATCH / B0_ROWS, 256, 0, stream>>>(obs, W_mean, b_mean, o_nh);
    k_finish<<<BATCH / 256, 256, 0, stream>>>(obs, W_logstd, b_logstd,
                                              prev_mean, prev_logstd,
                                              o_pm, o_ls, o_nls);
}

// Round 5
// 447.376 us; speedup vs baseline: 1.0697x; 1.0599x over previous
//
#include <hip/hip_runtime.h>
#include <math.h>

typedef unsigned short u16;
typedef unsigned int u32;
typedef __attribute__((ext_vector_type(8))) short short8;   // 8 bf16 = 4 VGPRs
typedef __attribute__((ext_vector_type(4))) float float4v;  // MFMA accum

// ---------- constants ----------
#define BATCH   8192
#define OBS     21
#define HID     512
#define NL      10
#define OVERALL 5632            // HID*(NL+1)
#define IN_DIM  5653            // OBS + OVERALL
#define ACT     8

// output element offsets (flat concat, fp32 elements)
#define O_PM   0
#define O_LS   65536
#define O_NH   131072
#define O_NM   (131072 + BATCH*OVERALL)     // 46268416
#define O_NLS  (O_NM + 65536)               // 46333952

// packed workspace: 10 x 512 x 512 bf16 weight blocks (K-contiguous)
#define WSP_TOTAL (10*512*512)
#define WSP_BYTES ((size_t)WSP_TOTAL * 2)

__device__ __forceinline__ u16 f2bf(float f) {
    u32 u = __float_as_uint(f);
    u32 r = (u + 0x7fffu + ((u >> 16) & 1u)) >> 16;   // RNE
    return (u16)r;
}
__device__ __forceinline__ u32 pkbf(float a, float b) {
    return (u32)f2bf(a) | ((u32)f2bf(b) << 16);
}
__device__ __forceinline__ void gload_lds16(const void* g, void* l) {
    __builtin_amdgcn_global_load_lds(
        (const __attribute__((address_space(1))) char*)g,
        (__attribute__((address_space(3))) char*)l, 16, 0, 0);
}

// ---------- kernel 0: repack banded W_mean blocks fp32 -> bf16 ----------
// 4 elements per thread (Wm rows are only 4-B aligned -> scalar loads, but
// 4-way ILP; ushort4 store is 8-B aligned).
__global__ __launch_bounds__(256) void k_pack(const float* __restrict__ Wm,
                                              u16* __restrict__ ws) {
    int idx4 = blockIdx.x * 256 + threadIdx.x;
    if (idx4 >= WSP_TOTAL / 4) return;
    int idx = idx4 * 4;
    int z = idx >> 18;
    int rem = idx & 262143;
    int n = rem >> 9, k = rem & 511;
    const float* g = Wm + (size_t)(512 * (z + 1) + n) * IN_DIM + OBS + 512 * z + k;
    ushort4 o;
    o.x = f2bf(g[0]); o.y = f2bf(g[1]); o.z = f2bf(g[2]); o.w = f2bf(g[3]);
    *(ushort4*)&ws[idx] = o;
}

// ---------- kernel 1: fused slice kernel (R0 verbatim — 131 us measured) ----
// grid (64, 11): block = 128 batch rows (gm) x one 512-col X slice (z).
//  z<10 : GEMM band z+1 (BN=512, out cols 512(z+1)..512(z+2)) + logstd partial
//  z==10: logstd partial + new_mean (band 11)
#define BM 128
#define BK 32
#define LDA 40                  // padded bf16 LDS rows for A
__global__ __launch_bounds__(1024, 4) void k_fused(
        const float* __restrict__ X,
        const float* __restrict__ Wm_raw,
        const u16* __restrict__ Wp,
        const float* __restrict__ Wls_raw,
        const float* __restrict__ b_mean,
        float* __restrict__ out_h,
        float* __restrict__ out_ls,
        float* __restrict__ out_mean,
        int packed) {
    __shared__ __attribute__((aligned(16))) u16 As[BM * LDA];      // 10.0 KB
    __shared__ __attribute__((aligned(16))) u16 Bs[512 * 32];      // 32 KB, xor-swizzled
    __shared__ __attribute__((aligned(16))) u16 Wt[16 * 520];      // 16.25 KB logstd slice
    u16* Wt2 = (u16*)Bs;                     // z==10 only: mean slice aliases Bs

    int t = threadIdx.x;
    int w = t >> 6, lane = t & 63;
    int quad = lane >> 4, r16 = lane & 15;
    int gm = blockIdx.x * BM;
    int z = blockIdx.y;
    bool mainz = (z < 10);
    int wm = (w >> 3) * 64;                  // GEMM wave tile: 2 m-pos x 8 n-pos
    int wn = (w & 7) * 64;

    // ---- stage logstd slice (bf16) + (z==10) mean slice ----
    {
        int n = t >> 7;                      // 0..7
        int k4 = (t & 127) * 4;
        const float* wr = Wls_raw + (size_t)n * IN_DIM + OBS + z * 512 + k4;
        u16* dst = &Wt[n * 520 + k4];
        dst[0] = f2bf(wr[0]); dst[1] = f2bf(wr[1]);
        dst[2] = f2bf(wr[2]); dst[3] = f2bf(wr[3]);
        if (!mainz) {
            const float* wr2 = Wm_raw + (size_t)(OVERALL + n) * IN_DIM + OBS + z * 512 + k4;
            u16* d2 = &Wt2[n * 520 + k4];
            d2[0] = f2bf(wr2[0]); d2[1] = f2bf(wr2[1]);
            d2[2] = f2bf(wr2[2]); d2[3] = f2bf(wr2[3]);
        }
    }

    // ---- A prefetch pointer: 1 float4 per thread per chunk ----
    int arow = t >> 3;                       // 0..127
    int acol = (t & 7) * 4;                  // 0..28
    const float* gA = X + (size_t)(gm + arow) * OVERALL + (size_t)z * 512 + acol;
    float4 areg = *(const float4*)(gA);      // chunk 0

    float4v acc[4][4];
#pragma unroll
    for (int i = 0; i < 4; i++)
#pragma unroll
        for (int j = 0; j < 4; j++) acc[i][j] = (float4v)0.f;
    float4v accL = (float4v)0.f;             // logstd (w<8) or mean (z==10, w>=8)

    for (int it = 0; it < 16; ++it) {
        int k0 = it * BK;
        __syncthreads();                     // prev frag reads done; LDS reusable
        // ---- A: cvt prefetched regs -> bf16 LDS ----
        {
            uint2 p;
            p.x = pkbf(areg.x, areg.y);
            p.y = pkbf(areg.z, areg.w);
            *(uint2*)&As[arow * LDA + acol] = p;
        }
        // ---- B: global -> LDS, xor-swizzled slots ----
        if (mainz) {
            if (packed) {
#pragma unroll
                for (int i2 = 0; i2 < 2; ++i2) {
                    int base_row = i2 * 256 + w * 16;
                    int row = base_row + (lane >> 2);
                    int slot = lane & 3;
                    int j = (slot - row) & 3;    // logical k-chunk in this slot
                    const u16* g = Wp + (size_t)z * 262144 + (size_t)row * 512 + k0 + j * 8;
                    gload_lds16(g, (char*)Bs + base_row * 64);
                }
            } else {
#pragma unroll
                for (int i2 = 0; i2 < 2; ++i2) {
                    int row = i2 * 256 + w * 16 + (lane >> 2);
                    int slot = lane & 3;
                    int j = (slot - row) & 3;
                    const float* g = Wm_raw + (size_t)(512 * (z + 1) + row) * IN_DIM
                                     + OBS + (size_t)z * 512 + k0 + j * 8;
                    uint4 q;
                    q.x = pkbf(g[0], g[1]); q.y = pkbf(g[2], g[3]);
                    q.z = pkbf(g[4], g[5]); q.w = pkbf(g[6], g[7]);
                    *(uint4*)&Bs[row * 32 + slot * 8] = q;
                }
            }
        }
        __syncthreads();                     // tile visible (drains B loads)
        if (it < 15) areg = *(const float4*)(gA + (it + 1) * BK);  // covered by MFMA

        if (mainz) {
            short8 bfr[4];
#pragma unroll
            for (int j = 0; j < 4; j++) {
                int n = wn + j * 16 + r16;
                int s = (quad + n) & 3;
                bfr[j] = *(const short8*)&Bs[n * 32 + s * 8];
            }
#pragma unroll
            for (int i2 = 0; i2 < 4; i2++) {
                short8 af = *(const short8*)&As[(wm + i2 * 16 + r16) * LDA + quad * 8];
#pragma unroll
                for (int j = 0; j < 4; j++)
                    acc[i2][j] = __builtin_amdgcn_mfma_f32_16x16x32_bf16(af, bfr[j], acc[i2][j], 0, 0, 0);
            }
        }
        if (w < 8) {                         // logstd partial: rows w*16..w*16+16
            short8 aL = *(const short8*)&As[(w * 16 + r16) * LDA + quad * 8];
            short8 bL = *(const short8*)&Wt[r16 * 520 + k0 + quad * 8];
            accL = __builtin_amdgcn_mfma_f32_16x16x32_bf16(aL, bL, accL, 0, 0, 0);
        } else if (!mainz) {                 // mean band: rows (w-8)*16..
            short8 aL = *(const short8*)&As[((w - 8) * 16 + r16) * LDA + quad * 8];
            short8 bL = *(const short8*)&Wt2[r16 * 520 + k0 + quad * 8];
            accL = __builtin_amdgcn_mfma_f32_16x16x32_bf16(aL, bL, accL, 0, 0, 0);
        }
    }

    // ---- epilogues.  C/D layout: col = lane&15, row = quad*4 + reg ----
    if (mainz) {
        int colblock = (z + 1) * 512;
#pragma unroll
        for (int j = 0; j < 4; j++) {
            int n_loc = wn + j * 16 + r16;
            float bias = b_mean[colblock + n_loc];
#pragma unroll
            for (int i2 = 0; i2 < 4; i2++) {
                int m0 = gm + wm + i2 * 16 + quad * 4;
#pragma unroll
                for (int r = 0; r < 4; r++) {
                    float v = acc[i2][j][r] + bias;
                    out_h[(size_t)(m0 + r) * OVERALL + colblock + n_loc] = fmaxf(v, 0.f);
                }
            }
        }
    }
    if (w < 8) {                             // logstd partial -> atomic
        if (r16 < ACT) {
#pragma unroll
            for (int r = 0; r < 4; r++) {
                int row = gm + w * 16 + quad * 4 + r;
                atomicAdd(&out_ls[(size_t)row * ACT + r16], accL[r]);
            }
        }
    } else if (!mainz) {                     // mean: exact, direct store
        if (r16 < ACT) {
            float bias = b_mean[OVERALL + r16];
#pragma unroll
            for (int r = 0; r < 4; r++) {
                int row = gm + (w - 8) * 16 + quad * 4 + r;
                out_mean[(size_t)row * ACT + r16] = accL[r] + bias;
            }
        }
    }
}

// ---------- kernel 2: fused epilogue --------------------------------------
// Merges old k_block0 (band 0: obs -> new_hidden cols 0..511, fp32 exact)
// and old k_finish (logstd obs-part + bias + tanh + copies) into one
// 256-block kernel. Old k_finish ran at 32 blocks (12% of chip, latency
// bound); here its work rides along at 256 blocks and reuses the obs LDS
// staging. Must launch AFTER k_fused (completes the out_ls atomics).
#define B0_ROWS 32
__global__ __launch_bounds__(256) void k_epi(const float* __restrict__ obs,
                                             const float* __restrict__ Wm,
                                             const float* __restrict__ b_mean,
                                             const float* __restrict__ Wls,
                                             const float* __restrict__ b_logstd,
                                             const float* __restrict__ pm,
                                             const float* __restrict__ pls,
                                             float* __restrict__ out_h,
                                             float* __restrict__ o_pm,
                                             float* __restrict__ o_lstd,
                                             float* __restrict__ o_nls) {
    __shared__ float w0[OBS * 512];           // transposed [k][n]  (42 KB)
    __shared__ float bias_s[512];
    __shared__ float obs_s[B0_ROWS * OBS];
    __shared__ float wobs[ACT * OBS];
    __shared__ float bls_s[ACT];
    int t = threadIdx.x;
    int b0 = blockIdx.x * B0_ROWS;
    for (int i = t; i < OBS * 512; i += 256) {
        int n = i / OBS, k = i - n * OBS;
        w0[k * 512 + n] = Wm[(size_t)n * IN_DIM + k];
    }
    for (int i = t; i < 512; i += 256) bias_s[i] = b_mean[i];
    for (int i = t; i < B0_ROWS * OBS; i += 256) obs_s[i] = obs[(size_t)b0 * OBS + i];
    if (t < ACT * OBS) wobs[t] = Wls[(size_t)(t / OBS) * IN_DIM + (t % OBS)];
    if (t < ACT) bls_s[t] = b_logstd[t];
    __syncthreads();

    // ---- phase A: band-0 GEMM, fp32 exact (old k_block0) ----
    {
        int n0 = (t & 127) * 4;
        int rh = t >> 7;
#pragma unroll 4
        for (int r = 0; r < 16; r++) {
            int row = rh * 16 + r;
            float acc0 = bias_s[n0], acc1 = bias_s[n0 + 1];
            float acc2 = bias_s[n0 + 2], acc3 = bias_s[n0 + 3];
#pragma unroll
            for (int k = 0; k < OBS; k++) {
                float xo = obs_s[row * OBS + k];
                const float* wr = &w0[k * 512 + n0];
                acc0 += xo * wr[0]; acc1 += xo * wr[1];
                acc2 += xo * wr[2]; acc3 += xo * wr[3];
            }
            float4 o;
            o.x = fmaxf(acc0, 0.f); o.y = fmaxf(acc1, 0.f);
            o.z = fmaxf(acc2, 0.f); o.w = fmaxf(acc3, 0.f);
            *(float4*)&out_h[(size_t)(b0 + row) * OVERALL + n0] = o;
        }
    }

    // ---- phase B: finisher (old k_finish), 8 threads per row ----
    {
        int rl = t >> 3;                      // 0..31 local row
        int n = t & 7;
        int row = b0 + rl;
        float a = bls_s[n];
#pragma unroll
        for (int k = 0; k < OBS; k++) a += obs_s[rl * OBS + k] * wobs[n * OBS + k];
        size_t off = (size_t)row * ACT + n;
        o_nls[off] += a;                      // completes the atomic partials
        o_pm[off] = pm[off];
        float l = pls[off];
        o_lstd[off] = -5.f + 3.5f * (tanhf(l) + 1.f);
    }
}

extern "C" void kernel_launch(void* const* d_in, const int* in_sizes, int n_in,
                              void* d_out, int out_size, void* d_ws, size_t ws_size,
                              hipStream_t stream) {
    const float* obs         = (const float*)d_in[0];
    const float* hidden0     = (const float*)d_in[1];
    const float* prev_mean   = (const float*)d_in[2];
    const float* prev_logstd = (const float*)d_in[3];
    const float* W_mean      = (const float*)d_in[4];
    const float* b_mean      = (const float*)d_in[5];
    const float* W_logstd    = (const float*)d_in[6];
    const float* b_logstd    = (const float*)d_in[7];

    float* out   = (float*)d_out;
    float* o_pm  = out + O_PM;
    float* o_ls  = out + O_LS;
    float* o_nh  = out + O_NH;
    float* o_nm  = out + O_NM;
    float* o_nls = out + O_NLS;
    u16*   ws    = (u16*)d_ws;

    int packed = (ws != nullptr && ws_size >= WSP_BYTES) ? 1 : 0;

    if (packed) {
        k_pack<<<(WSP_TOTAL / 4 + 255) / 256, 256, 0, stream>>>(W_mean, ws);
    }
    hipMemsetAsync(o_nls, 0, (size_t)BATCH * ACT * sizeof(float), stream);
    k_fused<<<dim3(BATCH / BM, NL + 1), 1024, 0, stream>>>(
        hidden0, W_mean, ws, W_logstd, b_mean, o_nh, o_nls, o_nm, packed);
    k_epi<<<BATCH / B0_ROWS, 256, 0, stream>>>(obs, W_mean, b_mean,
                                               W_logstd, b_logstd,
                                               prev_mean, prev_logstd,
                                               o_nh, o_pm, o_ls, o_nls);
}